// Round 6
// baseline (300.476 us; speedup 1.0000x reference)
//
#include <hip/hip_runtime.h>
#include <hip/hip_bf16.h>

#define BB   64
#define CING 96
#define MIDC 192
#define HH   56
#define WWD  56
#define HWSZ (HH*WWD)
#define COUTC 96
#define BNEPS 1e-5f

typedef __attribute__((ext_vector_type(8))) short short8;
typedef __attribute__((ext_vector_type(8))) unsigned short ushort8v;
typedef __attribute__((ext_vector_type(4))) float float4v;
typedef unsigned short ushort_t;
typedef unsigned int uint_t;

__device__ __forceinline__ float siluf(float v){ return v / (1.f + __expf(-v)); }
__device__ __forceinline__ ushort_t f2bs(float f){
    uint_t u = __float_as_uint(f);
    uint_t r = u + 0x7FFFu + ((u >> 16) & 1u);   // RNE; inputs are finite
    return (ushort_t)(r >> 16);
}
__device__ __forceinline__ float bs2f(ushort_t u){
    return __uint_as_float(((uint_t)u) << 16);
}
__device__ __forceinline__ uint_t pkbf(float a, float b){   // packed bf16 cvt (RNE)
    __hip_bfloat162 h = __float22bfloat162_rn(make_float2(a, b));
    union { __hip_bfloat162 h; uint_t u; } cv; cv.h = h; return cv.u;
}

// ---------------- k0: fold BNs, reorder+cast weights ---------------------------
__global__ __launch_bounds__(256) void k0_setup(
    const float* __restrict__ expand_w, const float* __restrict__ expand_bn,
    const float* __restrict__ dw_w, const float* __restrict__ dw_bn,
    const float* __restrict__ id_w, const float* __restrict__ id_bn,
    const float* __restrict__ merge_bn,
    const float* __restrict__ proj_w, const float* __restrict__ proj_bn,
    ushort_t* __restrict__ Aexp, float* __restrict__ ebias,
    float* __restrict__ w9f, float* __restrict__ cstf,
    ushort_t* __restrict__ Aproj, float* __restrict__ pscf, float* __restrict__ pshf)
{
    int i = blockIdx.x*256 + threadIdx.x;
    if (i < 4608) {                       // expand A: [m=192][k=96], BN-scale folded, shuffled
        int m = i/24, kq = (i%24)*4;
        int ic = (m&3)*48 + (m>>2);
        float sc0 = expand_bn[ic]*rsqrtf(expand_bn[3*MIDC+ic]+BNEPS);
        #pragma unroll
        for (int j=0;j<4;j++) Aexp[m*96+kq+j] = f2bs(expand_w[ic*96+kq+j]*sc0);
        if (kq==0) ebias[m] = expand_bn[MIDC+ic] - expand_bn[2*MIDC+ic]*sc0;
    } else if (i < 9216) {                // proj A: [m=96][k=192]
        int ii = i-4608; int m = ii/48, kq = (ii%48)*4;
        #pragma unroll
        for (int j=0;j<4;j++) Aproj[m*MIDC+kq+j] = f2bs(proj_w[m*MIDC+kq+j]);
        if (kq==0){
            float sc = proj_bn[m]*rsqrtf(proj_bn[3*COUTC+m]+BNEPS);
            pscf[m]=sc; pshf[m]=proj_bn[COUTC+m]-proj_bn[2*COUTC+m]*sc;
        }
    } else if (i < 9408) {                // dw folded taps
        int oc = i-9216;
        float sc1 = dw_bn[oc]    * rsqrtf(dw_bn[3*MIDC+oc]    + BNEPS);
        float sh1 = dw_bn[MIDC+oc]    - dw_bn[2*MIDC+oc]*sc1;
        float sc2 = id_bn[oc]    * rsqrtf(id_bn[3*MIDC+oc]    + BNEPS);
        float sh2 = id_bn[MIDC+oc]    - id_bn[2*MIDC+oc]*sc2;
        float sc3 = merge_bn[oc] * rsqrtf(merge_bn[3*MIDC+oc] + BNEPS);
        float sh3 = merge_bn[MIDC+oc] - merge_bn[2*MIDC+oc]*sc3;
        float A = sc3*sc1;
        #pragma unroll
        for (int j=0;j<9;j++) w9f[oc*9+j] = A*dw_w[oc*9+j];
        w9f[oc*9+4] += sc3*sc2*id_w[oc];
        cstf[oc] = sc3*(sh1+sh2) + sh3;
    }
}

// ---------------- k1: expand GEMM (MFMA, operand-swapped) + BN + SiLU -> E -----
#define LDB1T 104
__global__ __launch_bounds__(256) void k1_expand(
    const float* __restrict__ x,
    const ushort_t* __restrict__ Aexp,
    const float* __restrict__ ebias,
    ushort_t* __restrict__ EY)
{
    __shared__ __align__(16) ushort_t BsT[64*LDB1T];    // 13,312 B  [n][k]
    __shared__ float ebL[MIDC];
    const int t = threadIdx.x;
    const int p0 = blockIdx.x*64, b = blockIdx.y;

    if (t < MIDC) ebL[t] = ebias[t];
    {                                                   // stage B transposed: [n=64][k=96]
        const int n  = t & 63;
        const int kb = (t >> 6)*24;
        #pragma unroll
        for (int ii = 0; ii < 3; ii++) {
            int k8 = kb + ii*8;
            const float* xp = x + ((size_t)(b*CING + k8))*HWSZ + p0 + n;
            float v[8];
            #pragma unroll
            for (int j = 0; j < 8; j++) v[j] = xp[(size_t)j*HWSZ];
            uint4 uu;
            uu.x = pkbf(v[0],v[1]); uu.y = pkbf(v[2],v[3]);
            uu.z = pkbf(v[4],v[5]); uu.w = pkbf(v[6],v[7]);
            *(uint4*)(&BsT[n*LDB1T + k8]) = uu;
        }
    }

    const int lane = t & 63, wv = t >> 6;
    const int l = lane & 15, q = lane >> 4;
    short8 af[3][3];                                    // A straight from global (L2-hot)
    #pragma unroll
    for (int ks = 0; ks < 3; ks++)
        #pragma unroll
        for (int mi = 0; mi < 3; mi++)
            af[ks][mi] = *(const short8*)(Aexp + ((wv*3+mi)*16 + l)*96 + ks*32 + q*8);
    __syncthreads();

    float4v acc[3][4];
    #pragma unroll
    for (int mi=0;mi<3;mi++)
        #pragma unroll
        for (int nt=0;nt<4;nt++) acc[mi][nt] = (float4v){0.f,0.f,0.f,0.f};
    #pragma unroll
    for (int ks = 0; ks < 3; ks++) {
        const int k0 = ks*32;
        short8 bf[4];
        #pragma unroll
        for (int nt = 0; nt < 4; nt++)
            bf[nt] = *(const short8*)(&BsT[(nt*16 + l)*LDB1T + k0 + q*8]);
        #pragma unroll
        for (int mi = 0; mi < 3; mi++)
            #pragma unroll
            for (int nt = 0; nt < 4; nt++)   // swapped: pixel->regs, m->lanes
                acc[mi][nt] = __builtin_amdgcn_mfma_f32_16x16x32_bf16(bf[nt], af[ks][mi], acc[mi][nt], 0,0,0);
    }
    #pragma unroll
    for (int mi = 0; mi < 3; mi++) {
        const int m = (wv*3+mi)*16 + l;
        const float eb = ebL[m];
        ushort_t* rp = EY + (size_t)(b*MIDC + m)*HWSZ + p0 + q*4;
        #pragma unroll
        for (int nt = 0; nt < 4; nt++) {
            float s0 = siluf(acc[mi][nt][0] + eb);
            float s1 = siluf(acc[mi][nt][1] + eb);
            float s2 = siluf(acc[mi][nt][2] + eb);
            float s3 = siluf(acc[mi][nt][3] + eb);
            uint2 w2; w2.x = pkbf(s0,s1); w2.y = pkbf(s2,s3);
            *(uint2*)(rp + nt*16) = w2;
        }
    }
}

// ---------------- k2: shifted dw3x3 + SiLU, 2 waves/plane, in-place ------------
__global__ __launch_bounds__(256) void k2_dw(
    ushort_t* __restrict__ EY,
    const float* __restrict__ w9f,
    const float* __restrict__ cstf,
    float* __restrict__ sums)
{
    __shared__ float wred[4];
    const int t = threadIdx.x;
    const int lane = t & 63, w = t >> 6;
    const int pl = w >> 1, half = w & 1;
    const int oc = blockIdx.x*2 + pl;
    const int b  = blockIdx.y;
    ushort_t* plane = EY + (size_t)(b*MIDC + oc)*HWSZ;
    const int g  = oc & 3;
    const int dy = (g==0)?-1:(g==2?1:0);
    const int dx = (g==1)?-1:(g==3?1:0);
    float w9[9];
    #pragma unroll
    for (int j=0;j<9;j++) w9[j] = w9f[oc*9+j];
    const float cst = cstf[oc];

    const int c  = lane;
    const int cx = c + dx;
    const bool laneok = (c < WWD) & (cx >= 0) & (cx < WWD);
    const int cxc = min(max(cx, 0), WWD-1);
    const bool cval = (c < WWD);

    // conflict rows (other half overwrites them post-barrier): preload into regs
    int ya = -1000, yb = -1000;
    if (half == 0) { if (dy == 1) { ya = 27; yb = 28; } else if (dy == 0) { ya = 28; } }
    else           { if (dy == -1){ ya = 27; yb = 28; } else if (dy == 0) { ya = 27; } }
    float va = 0.f, vb = 0.f;
    if (ya != -1000) {
        float v = bs2f(plane[(ya+dy)*WWD + cxc]);
        va = laneok ? v : 0.f;
    }
    if (yb != -1000) {
        float v = bs2f(plane[(yb+dy)*WWD + cxc]);
        vb = laneok ? v : 0.f;
    }
    __syncthreads();

    const int ys = half ? 27 : -1;
    const int ye = half ? 56 : 28;     // inclusive
    const int so = half ? 29 : 1;      // first storing iteration (stores row y-1)
    float p1 = 0.f, p0 = 0.f, partial = 0.f;
    for (int y = ys; y <= ye; ++y) {
        int yy = y + dy;
        float val = 0.f;
        if (((unsigned)y < HH) & ((unsigned)yy < HH)) {
            float v = bs2f(plane[yy*WWD + cxc]);
            val = laneok ? v : 0.f;
        }
        if (y == ya) val = va;
        if (y == yb) val = vb;
        float vl = __shfl_up(val, 1);  if (lane == 0) vl = 0.f;
        float vr = __shfl_down(val, 1);               // lane63 garbage: c>=56, never stored
        float a0 = w9[0]*vl + w9[1]*val + w9[2]*vr;   // -> out[y+1]
        float a1 = w9[3]*vl + w9[4]*val + w9[5]*vr;   // -> out[y]
        float a2 = w9[6]*vl + w9[7]*val + w9[8]*vr + cst;  // -> out[y-1] (+bias once)
        if (y >= so) {
            float yv = siluf(p1 + a2);
            if (cval) {
                plane[(y-1)*WWD + c] = f2bs(yv);
                partial += yv;
            }
        }
        p1 = p0 + a1;
        p0 = a0;
    }
    #pragma unroll
    for (int off=1; off<64; off<<=1) partial += __shfl_xor(partial, off);
    if (lane == 0) wred[w] = partial;
    __syncthreads();
    if (t < 2) sums[b*MIDC + blockIdx.x*2 + t] = wred[t*2] + wred[t*2+1];
}

// ---------------- k3: SE -------------------------------------------------------
__global__ __launch_bounds__(192) void k3_se(
    const float* __restrict__ sums,
    const float* __restrict__ se_red_w, const float* __restrict__ se_red_b,
    const float* __restrict__ se_exp_w, const float* __restrict__ se_exp_b,
    float* __restrict__ sews)
{
    __shared__ float meanL[MIDC];
    __shared__ float redL[24];
    const int b = blockIdx.x, t = threadIdx.x;
    meanL[t] = sums[b*MIDC + t] * (1.f/(float)HWSZ);
    __syncthreads();
    if (t < 24) {
        int g = t >> 1;
        float a = se_red_b[t];
        #pragma unroll
        for (int i = 0; i < 16; i++) a += meanL[g*16+i] * se_red_w[t*16+i];
        redL[t] = fmaxf(a, 0.f);
    }
    __syncthreads();
    int g = t >> 4;
    float a = se_exp_b[t] + redL[g*2]*se_exp_w[t*2] + redL[g*2+1]*se_exp_w[t*2+1];
    sews[b*MIDC + t] = 1.f/(1.f + __expf(-a));
}

// ---------------- k4: proj GEMM (MFMA swapped, SE folded) + BN + res + SiLU ----
#define LDB4T 200
__global__ __launch_bounds__(256) void k4_proj(
    const ushort_t* __restrict__ EY,
    const float* __restrict__ sews,
    const ushort_t* __restrict__ Aproj,
    const float* __restrict__ pscf, const float* __restrict__ pshf,
    const float* __restrict__ x,
    float* __restrict__ out)
{
    __shared__ __align__(16) ushort_t BsT[64*LDB4T];     // 25,600 B  [n][k]
    __shared__ float pscL[COUTC], pshL[COUTC];
    const int t = threadIdx.x;
    const int p0 = blockIdx.x*64, b = blockIdx.y;
    if (t < COUTC) { pscL[t] = pscf[t]; pshL[t] = pshf[t]; }
    {                                                   // stage B transposed, SE folded
        const int n  = t & 63;
        const int kb = (t >> 6)*48;
        const float* sew = sews + b*MIDC;
        #pragma unroll
        for (int ii = 0; ii < 6; ii++) {
            int k8 = kb + ii*8;
            const ushort_t* ep = EY + ((size_t)(b*MIDC + k8))*HWSZ + p0 + n;
            float v[8];
            #pragma unroll
            for (int j = 0; j < 8; j++)
                v[j] = bs2f(ep[(size_t)j*HWSZ]) * sew[k8+j];
            uint4 uu;
            uu.x = pkbf(v[0],v[1]); uu.y = pkbf(v[2],v[3]);
            uu.z = pkbf(v[4],v[5]); uu.w = pkbf(v[6],v[7]);
            *(uint4*)(&BsT[n*LDB4T + k8]) = uu;
        }
    }

    const int lane = t & 63, wv = t >> 6;
    const int l = lane & 15, q = lane >> 4;
    const int mh = wv >> 1, nh = wv & 1;
    short8 af[6][3];
    #pragma unroll
    for (int ks = 0; ks < 6; ks++)
        #pragma unroll
        for (int mi = 0; mi < 3; mi++)
            af[ks][mi] = *(const short8*)(Aproj + ((mh*3+mi)*16 + l)*MIDC + ks*32 + q*8);
    __syncthreads();

    float4v acc[3][2];
    #pragma unroll
    for (int mi=0;mi<3;mi++)
        #pragma unroll
        for (int nt=0;nt<2;nt++) acc[mi][nt] = (float4v){0.f,0.f,0.f,0.f};
    #pragma unroll
    for (int ks = 0; ks < 6; ks++) {
        const int k0 = ks*32;
        short8 bf[2];
        #pragma unroll
        for (int nt = 0; nt < 2; nt++)
            bf[nt] = *(const short8*)(&BsT[(nh*32 + nt*16 + l)*LDB4T + k0 + q*8]);
        #pragma unroll
        for (int mi = 0; mi < 3; mi++)
            #pragma unroll
            for (int nt = 0; nt < 2; nt++)   // swapped: pixel->regs, m->lanes
                acc[mi][nt] = __builtin_amdgcn_mfma_f32_16x16x32_bf16(bf[nt], af[ks][mi], acc[mi][nt], 0,0,0);
    }
    #pragma unroll
    for (int mi = 0; mi < 3; mi++) {
        const int m = (mh*3+mi)*16 + l;
        const float sc = pscL[m], sh = pshL[m];
        const size_t rowb = (size_t)(b*COUTC + m)*HWSZ + p0 + nh*32 + q*4;
        #pragma unroll
        for (int nt = 0; nt < 2; nt++) {
            const size_t idx = rowb + nt*16;
            float4 xr = *(const float4*)(x + idx);
            float4 o;
            o.x = siluf(acc[mi][nt][0]*sc + sh + xr.x);
            o.y = siluf(acc[mi][nt][1]*sc + sh + xr.y);
            o.z = siluf(acc[mi][nt][2]*sc + sh + xr.z);
            o.w = siluf(acc[mi][nt][3]*sc + sh + xr.w);
            *(float4*)(out + idx) = o;
        }
    }
}

extern "C" void kernel_launch(void* const* d_in, const int* in_sizes, int n_in,
                              void* d_out, int out_size, void* d_ws, size_t ws_size,
                              hipStream_t stream)
{
    const float* x         = (const float*)d_in[0];
    const float* expand_w  = (const float*)d_in[1];
    const float* expand_bn = (const float*)d_in[2];
    const float* dw_w      = (const float*)d_in[3];
    const float* dw_bn     = (const float*)d_in[4];
    const float* id_w      = (const float*)d_in[5];
    const float* id_bn     = (const float*)d_in[6];
    const float* merge_bn  = (const float*)d_in[7];
    const float* se_red_w  = (const float*)d_in[8];
    const float* se_red_b  = (const float*)d_in[9];
    const float* se_exp_w  = (const float*)d_in[10];
    const float* se_exp_b  = (const float*)d_in[11];
    const float* proj_w    = (const float*)d_in[12];
    const float* proj_bn   = (const float*)d_in[13];

    char* base = (char*)d_ws;
    size_t off = 0;
    ushort_t* EY   = (ushort_t*)(base + off); off += (size_t)BB*MIDC*HWSZ*2;  // 77,070,336
    float* sums    = (float*)(base + off);    off += BB*MIDC*4;
    float* sews    = (float*)(base + off);    off += BB*MIDC*4;
    ushort_t* Aexp = (ushort_t*)(base + off); off += MIDC*CING*2;
    ushort_t* Aproj= (ushort_t*)(base + off); off += COUTC*MIDC*2;
    float* ebias   = (float*)(base + off);    off += MIDC*4;
    float* w9f     = (float*)(base + off);    off += MIDC*9*4;
    float* cstf    = (float*)(base + off);    off += MIDC*4;
    float* pscf    = (float*)(base + off);    off += COUTC*4;
    float* pshf    = (float*)(base + off);    off += COUTC*4;

    k0_setup<<<dim3(37), dim3(256), 0, stream>>>(
        expand_w, expand_bn, dw_w, dw_bn, id_w, id_bn, merge_bn, proj_w, proj_bn,
        Aexp, ebias, w9f, cstf, Aproj, pscf, pshf);
    k1_expand<<<dim3(HWSZ/64, BB), dim3(256), 0, stream>>>(x, Aexp, ebias, EY);
    k2_dw<<<dim3(MIDC/2, BB), dim3(256), 0, stream>>>(EY, w9f, cstf, sums);
    k3_se<<<dim3(BB), dim3(192), 0, stream>>>(
        sums, se_red_w, se_red_b, se_exp_w, se_exp_b, sews);
    k4_proj<<<dim3(HWSZ/64, BB), dim3(256), 0, stream>>>(
        EY, sews, Aproj, pscf, pshf, x, (float*)d_out);
}

// Round 7
// 279.482 us; speedup vs baseline: 1.0751x; 1.0751x over previous
//
#include <hip/hip_runtime.h>
#include <hip/hip_bf16.h>

#define BB   64
#define CING 96
#define MIDC 192
#define HH   56
#define WWD  56
#define HWSZ (HH*WWD)
#define COUTC 96
#define BNEPS 1e-5f

typedef __attribute__((ext_vector_type(8))) short short8;
typedef __attribute__((ext_vector_type(8))) unsigned short ushort8v;
typedef __attribute__((ext_vector_type(4))) float float4v;
typedef unsigned short ushort_t;
typedef unsigned int uint_t;

__device__ __forceinline__ float siluf(float v){ return v / (1.f + __expf(-v)); }
__device__ __forceinline__ ushort_t f2bs(float f){
    uint_t u = __float_as_uint(f);
    uint_t r = u + 0x7FFFu + ((u >> 16) & 1u);   // RNE; inputs are finite
    return (ushort_t)(r >> 16);
}
__device__ __forceinline__ float bs2f(ushort_t u){
    return __uint_as_float(((uint_t)u) << 16);
}
__device__ __forceinline__ uint_t pkbf(float a, float b){   // packed bf16 cvt (RNE)
    __hip_bfloat162 h = __float22bfloat162_rn(make_float2(a, b));
    union { __hip_bfloat162 h; uint_t u; } cv; cv.h = h; return cv.u;
}
__device__ __forceinline__ float bslo(uint_t x){ return __uint_as_float(x << 16); }
__device__ __forceinline__ float bshi(uint_t x){ return __uint_as_float(x & 0xFFFF0000u); }

// ---------------- k0: fold BNs, reorder+cast weights ---------------------------
__global__ __launch_bounds__(256) void k0_setup(
    const float* __restrict__ expand_w, const float* __restrict__ expand_bn,
    const float* __restrict__ dw_w, const float* __restrict__ dw_bn,
    const float* __restrict__ id_w, const float* __restrict__ id_bn,
    const float* __restrict__ merge_bn,
    const float* __restrict__ proj_w, const float* __restrict__ proj_bn,
    ushort_t* __restrict__ Aexp, float* __restrict__ ebias,
    float* __restrict__ w9f, float* __restrict__ cstf,
    ushort_t* __restrict__ Aproj, float* __restrict__ pscf, float* __restrict__ pshf)
{
    int i = blockIdx.x*256 + threadIdx.x;
    if (i < 4608) {                       // expand A: [m=192][k=96], BN-scale folded, shuffled
        int m = i/24, kq = (i%24)*4;
        int ic = (m&3)*48 + (m>>2);
        float sc0 = expand_bn[ic]*rsqrtf(expand_bn[3*MIDC+ic]+BNEPS);
        #pragma unroll
        for (int j=0;j<4;j++) Aexp[m*96+kq+j] = f2bs(expand_w[ic*96+kq+j]*sc0);
        if (kq==0) ebias[m] = expand_bn[MIDC+ic] - expand_bn[2*MIDC+ic]*sc0;
    } else if (i < 9216) {                // proj A: [m=96][k=192]
        int ii = i-4608; int m = ii/48, kq = (ii%48)*4;
        #pragma unroll
        for (int j=0;j<4;j++) Aproj[m*MIDC+kq+j] = f2bs(proj_w[m*MIDC+kq+j]);
        if (kq==0){
            float sc = proj_bn[m]*rsqrtf(proj_bn[3*COUTC+m]+BNEPS);
            pscf[m]=sc; pshf[m]=proj_bn[COUTC+m]-proj_bn[2*COUTC+m]*sc;
        }
    } else if (i < 9408) {                // dw folded taps
        int oc = i-9216;
        float sc1 = dw_bn[oc]    * rsqrtf(dw_bn[3*MIDC+oc]    + BNEPS);
        float sh1 = dw_bn[MIDC+oc]    - dw_bn[2*MIDC+oc]*sc1;
        float sc2 = id_bn[oc]    * rsqrtf(id_bn[3*MIDC+oc]    + BNEPS);
        float sh2 = id_bn[MIDC+oc]    - id_bn[2*MIDC+oc]*sc2;
        float sc3 = merge_bn[oc] * rsqrtf(merge_bn[3*MIDC+oc] + BNEPS);
        float sh3 = merge_bn[MIDC+oc] - merge_bn[2*MIDC+oc]*sc3;
        float A = sc3*sc1;
        #pragma unroll
        for (int j=0;j<9;j++) w9f[oc*9+j] = A*dw_w[oc*9+j];
        w9f[oc*9+4] += sc3*sc2*id_w[oc];
        cstf[oc] = sc3*(sh1+sh2) + sh3;
    }
}

// ---------------- k1: expand GEMM (MFMA, A in regs) + BN + SiLU -> E (round-5) --
#define LDB1T 104
__global__ __launch_bounds__(256) void k1_expand(
    const float* __restrict__ x,
    const ushort_t* __restrict__ Aexp,
    const float* __restrict__ ebias,
    ushort_t* __restrict__ EY)
{
    __shared__ __align__(16) ushort_t BsT[64*LDB1T];    // 13,312 B  [n][k]
    __shared__ float ebL[MIDC];
    const int t = threadIdx.x;
    const int p0 = blockIdx.x*64, b = blockIdx.y;

    if (t < MIDC) ebL[t] = ebias[t];
    {                                                   // stage B transposed: [n=64][k=96]
        const int n  = t & 63;
        const int kb = (t >> 6)*24;
        #pragma unroll
        for (int ii = 0; ii < 3; ii++) {
            int k8 = kb + ii*8;
            const float* xp = x + ((size_t)(b*CING + k8))*HWSZ + p0 + n;
            ushort8v u;
            #pragma unroll
            for (int j = 0; j < 8; j++) u[j] = f2bs(xp[(size_t)j*HWSZ]);
            *(ushort8v*)(&BsT[n*LDB1T + k8]) = u;
        }
    }

    const int lane = t & 63, wv = t >> 6;
    const int l = lane & 15, q = lane >> 4;
    short8 af[3][3];                                    // A straight from global (L2-hot)
    #pragma unroll
    for (int ks = 0; ks < 3; ks++)
        #pragma unroll
        for (int mi = 0; mi < 3; mi++)
            af[ks][mi] = *(const short8*)(Aexp + ((wv*3+mi)*16 + l)*96 + ks*32 + q*8);
    __syncthreads();

    float4v acc[3][4];
    #pragma unroll
    for (int mi=0;mi<3;mi++)
        #pragma unroll
        for (int nt=0;nt<4;nt++) acc[mi][nt] = (float4v){0.f,0.f,0.f,0.f};
    #pragma unroll
    for (int ks = 0; ks < 3; ks++) {
        const int k0 = ks*32;
        short8 bf[4];
        #pragma unroll
        for (int nt = 0; nt < 4; nt++)
            bf[nt] = *(const short8*)(&BsT[(nt*16 + l)*LDB1T + k0 + q*8]);
        #pragma unroll
        for (int mi = 0; mi < 3; mi++)
            #pragma unroll
            for (int nt = 0; nt < 4; nt++)
                acc[mi][nt] = __builtin_amdgcn_mfma_f32_16x16x32_bf16(af[ks][mi], bf[nt], acc[mi][nt], 0,0,0);
    }
    #pragma unroll
    for (int mi = 0; mi < 3; mi++) {
        #pragma unroll
        for (int r = 0; r < 4; r++) {
            int m = (wv*3+mi)*16 + q*4 + r;
            float eb = ebL[m];
            size_t rowb = (size_t)(b*MIDC + m)*HWSZ + p0 + l;
            #pragma unroll
            for (int nt = 0; nt < 4; nt++)
                EY[rowb + nt*16] = f2bs(siluf(acc[mi][nt][r] + eb));
        }
    }
}

// ---------------- k2: shifted dw3x3 + SiLU, 4-col packed, in-place -------------
// Block = 128 thr (2 waves = halves). Wave: 4 plane-groups (same shift dir),
// lane group lg handles one plane-half; li in [0,14) covers cols 4*li..4*li+3.
template<int DY, int DX>
__device__ __forceinline__ float dw_plane(
    ushort_t* __restrict__ plane, const float* __restrict__ w9, float cst,
    int li, int h, bool act)
{
    // conflict rows (other half overwrites them after the barrier): preload
    uint2 pA = make_uint2(0u,0u), pB = make_uint2(0u,0u);
    int rA = -100, rB = -100;
    if (h == 0) { if (DY==1){ rA=28; rB=29; } else if (DY==0){ rA=28; } }
    else        { if (DY==-1){ rA=26; rB=27; } else if (DY==0){ rA=27; } }
    const ushort_t* pl = plane + li*4;
    if (rA >= 0) pA = *(const uint2*)(pl + rA*WWD);
    if (rB >= 0) pB = *(const uint2*)(pl + rB*WWD);
    __syncthreads();

    const int ys = h ? 27 : -1;
    const int so = h ? 29 : 1;

    auto loadrow = [&](int y) -> uint2 {
        int yy = y + DY;
        uint2 u = make_uint2(0u,0u);
        if (((unsigned)y < (unsigned)HH) && ((unsigned)yy < (unsigned)HH)) {
            if (yy == rA)      u = pA;
            else if (yy == rB) u = pB;
            else               u = *(const uint2*)(pl + yy*WWD);
        }
        return u;
    };

    float p0[4] = {0,0,0,0}, p1[4] = {0,0,0,0};
    float partial = 0.f;
    uint2 u = loadrow(ys);
    for (int y = ys; y <= ys + 29; ++y) {
        uint2 un = loadrow(y + 1);              // prefetch BEFORE this iter's store
        uint_t lhi = __shfl_up(u.y, 1);         // cols c0-2,c0-1
        uint_t rlo = __shfl_down(u.x, 1);       // cols c0+4,c0+5
        if (li == 0)  lhi = 0u;
        if (li == 13) rlo = 0u;
        float s[8];
        s[0]=bslo(lhi); s[1]=bshi(lhi);
        s[2]=bslo(u.x); s[3]=bshi(u.x);
        s[4]=bslo(u.y); s[5]=bshi(u.y);
        s[6]=bslo(rlo); s[7]=bshi(rlo);
        if (li == 0)  s[DX+1] = 0.f;            // conv zero-pad at S[-1]
        if (li == 13) s[DX+6] = 0.f;            // conv zero-pad at S[56]
        float o[4];
        #pragma unroll
        for (int j = 0; j < 4; j++) {
            float t0 = s[j+DX+1], t1 = s[j+DX+2], t2 = s[j+DX+3];
            o[j]  = p1[j] + (w9[6]*t0 + w9[7]*t1 + w9[8]*t2) + cst;
            p1[j] = p0[j] + (w9[3]*t0 + w9[4]*t1 + w9[5]*t2);
            p0[j] =          w9[0]*t0 + w9[1]*t1 + w9[2]*t2;
        }
        if (y >= so && act) {
            float y0=siluf(o[0]), y1=siluf(o[1]), y2=siluf(o[2]), y3=siluf(o[3]);
            uint2 w2; w2.x = pkbf(y0,y1); w2.y = pkbf(y2,y3);
            *(uint2*)(plane + (size_t)(y-1)*WWD + li*4) = w2;
            partial += (y0+y1) + (y2+y3);
        }
        u = un;
    }
    #pragma unroll
    for (int off = 1; off < 16; off <<= 1) partial += __shfl_xor(partial, off);
    return partial;
}

__global__ __launch_bounds__(128) void k2_dw(
    ushort_t* __restrict__ EY,
    const float* __restrict__ w9f,
    const float* __restrict__ cstf,
    float* __restrict__ sums)
{
    __shared__ float wred[8];
    const int t = threadIdx.x;
    const int lane = t & 63, h = t >> 6;
    const int lg = lane >> 4, li = lane & 15;
    const int gi = blockIdx.x >> 2, r = blockIdx.x & 3;   // r = shift group (uniform)
    const int b = blockIdx.y;
    const int oc = gi*16 + r + lg*4;
    ushort_t* plane = EY + (size_t)(b*MIDC + oc)*HWSZ;
    float w9[9];
    #pragma unroll
    for (int j = 0; j < 9; j++) w9[j] = w9f[oc*9+j];
    const float cst = cstf[oc];
    const bool act = (li < 14);
    float ps;
    if      (r == 0) ps = dw_plane<-1, 0>(plane, w9, cst, li, h, act);
    else if (r == 1) ps = dw_plane< 0,-1>(plane, w9, cst, li, h, act);
    else if (r == 2) ps = dw_plane< 1, 0>(plane, w9, cst, li, h, act);
    else             ps = dw_plane< 0, 1>(plane, w9, cst, li, h, act);
    if (li == 0) wred[h*4 + lg] = ps;
    __syncthreads();
    if (t < 4) sums[b*MIDC + gi*16 + r + t*4] = wred[t] + wred[4 + t];
}

// ---------------- k3: SE -------------------------------------------------------
__global__ __launch_bounds__(192) void k3_se(
    const float* __restrict__ sums,
    const float* __restrict__ se_red_w, const float* __restrict__ se_red_b,
    const float* __restrict__ se_exp_w, const float* __restrict__ se_exp_b,
    float* __restrict__ sews)
{
    __shared__ float meanL[MIDC];
    __shared__ float redL[24];
    const int b = blockIdx.x, t = threadIdx.x;
    meanL[t] = sums[b*MIDC + t] * (1.f/(float)HWSZ);
    __syncthreads();
    if (t < 24) {
        int g = t >> 1;
        float a = se_red_b[t];
        #pragma unroll
        for (int i = 0; i < 16; i++) a += meanL[g*16+i] * se_red_w[t*16+i];
        redL[t] = fmaxf(a, 0.f);
    }
    __syncthreads();
    int g = t >> 4;
    float a = se_exp_b[t] + redL[g*2]*se_exp_w[t*2] + redL[g*2+1]*se_exp_w[t*2+1];
    sews[b*MIDC + t] = 1.f/(1.f + __expf(-a));
}

// ---------------- k4: proj GEMM (MFMA, A in regs, SE folded) (round-5) ---------
#define LDB4T 200
__global__ __launch_bounds__(256) void k4_proj(
    const ushort_t* __restrict__ EY,
    const float* __restrict__ sews,
    const ushort_t* __restrict__ Aproj,
    const float* __restrict__ pscf, const float* __restrict__ pshf,
    const float* __restrict__ x,
    float* __restrict__ out)
{
    __shared__ __align__(16) ushort_t BsT[64*LDB4T];     // 25,600 B  [n][k]
    __shared__ float pscL[COUTC], pshL[COUTC];
    const int t = threadIdx.x;
    const int p0 = blockIdx.x*64, b = blockIdx.y;
    if (t < COUTC) { pscL[t] = pscf[t]; pshL[t] = pshf[t]; }
    {                                                   // stage B transposed, SE folded
        const int n  = t & 63;
        const int kb = (t >> 6)*48;
        const float* sew = sews + b*MIDC;
        #pragma unroll
        for (int ii = 0; ii < 6; ii++) {
            int k8 = kb + ii*8;
            const ushort_t* ep = EY + ((size_t)(b*MIDC + k8))*HWSZ + p0 + n;
            ushort8v u;
            #pragma unroll
            for (int j = 0; j < 8; j++)
                u[j] = f2bs(bs2f(ep[(size_t)j*HWSZ]) * sew[k8+j]);
            *(ushort8v*)(&BsT[n*LDB4T + k8]) = u;
        }
    }

    const int lane = t & 63, wv = t >> 6;
    const int l = lane & 15, q = lane >> 4;
    const int mh = wv >> 1, nh = wv & 1;
    short8 af[6][3];
    #pragma unroll
    for (int ks = 0; ks < 6; ks++)
        #pragma unroll
        for (int mi = 0; mi < 3; mi++)
            af[ks][mi] = *(const short8*)(Aproj + ((mh*3+mi)*16 + l)*MIDC + ks*32 + q*8);
    __syncthreads();

    float4v acc[3][2];
    #pragma unroll
    for (int mi=0;mi<3;mi++)
        #pragma unroll
        for (int nt=0;nt<2;nt++) acc[mi][nt] = (float4v){0.f,0.f,0.f,0.f};
    #pragma unroll
    for (int ks = 0; ks < 6; ks++) {
        const int k0 = ks*32;
        short8 bf[2];
        #pragma unroll
        for (int nt = 0; nt < 2; nt++)
            bf[nt] = *(const short8*)(&BsT[(nh*32 + nt*16 + l)*LDB4T + k0 + q*8]);
        #pragma unroll
        for (int mi = 0; mi < 3; mi++)
            #pragma unroll
            for (int nt = 0; nt < 2; nt++)
                acc[mi][nt] = __builtin_amdgcn_mfma_f32_16x16x32_bf16(af[ks][mi], bf[nt], acc[mi][nt], 0,0,0);
    }
    #pragma unroll
    for (int mi = 0; mi < 3; mi++) {
        #pragma unroll
        for (int r = 0; r < 4; r++) {
            int m = (mh*3+mi)*16 + q*4 + r;
            float sc = pscL[m], sh = pshL[m];
            size_t rowb = (size_t)(b*COUTC + m)*HWSZ + p0 + nh*32 + l;
            #pragma unroll
            for (int nt = 0; nt < 2; nt++) {
                size_t idx = rowb + nt*16;
                float v = acc[mi][nt][r]*sc + sh + x[idx];
                out[idx] = siluf(v);
            }
        }
    }
}

extern "C" void kernel_launch(void* const* d_in, const int* in_sizes, int n_in,
                              void* d_out, int out_size, void* d_ws, size_t ws_size,
                              hipStream_t stream)
{
    const float* x         = (const float*)d_in[0];
    const float* expand_w  = (const float*)d_in[1];
    const float* expand_bn = (const float*)d_in[2];
    const float* dw_w      = (const float*)d_in[3];
    const float* dw_bn     = (const float*)d_in[4];
    const float* id_w      = (const float*)d_in[5];
    const float* id_bn     = (const float*)d_in[6];
    const float* merge_bn  = (const float*)d_in[7];
    const float* se_red_w  = (const float*)d_in[8];
    const float* se_red_b  = (const float*)d_in[9];
    const float* se_exp_w  = (const float*)d_in[10];
    const float* se_exp_b  = (const float*)d_in[11];
    const float* proj_w    = (const float*)d_in[12];
    const float* proj_bn   = (const float*)d_in[13];

    char* base = (char*)d_ws;
    size_t off = 0;
    ushort_t* EY   = (ushort_t*)(base + off); off += (size_t)BB*MIDC*HWSZ*2;  // 77,070,336
    float* sums    = (float*)(base + off);    off += BB*MIDC*4;
    float* sews    = (float*)(base + off);    off += BB*MIDC*4;
    ushort_t* Aexp = (ushort_t*)(base + off); off += MIDC*CING*2;
    ushort_t* Aproj= (ushort_t*)(base + off); off += COUTC*MIDC*2;
    float* ebias   = (float*)(base + off);    off += MIDC*4;
    float* w9f     = (float*)(base + off);    off += MIDC*9*4;
    float* cstf    = (float*)(base + off);    off += MIDC*4;
    float* pscf    = (float*)(base + off);    off += COUTC*4;
    float* pshf    = (float*)(base + off);    off += COUTC*4;

    k0_setup<<<dim3(37), dim3(256), 0, stream>>>(
        expand_w, expand_bn, dw_w, dw_bn, id_w, id_bn, merge_bn, proj_w, proj_bn,
        Aexp, ebias, w9f, cstf, Aproj, pscf, pshf);
    k1_expand<<<dim3(HWSZ/64, BB), dim3(256), 0, stream>>>(x, Aexp, ebias, EY);
    k2_dw<<<dim3(48, BB), dim3(128), 0, stream>>>(EY, w9f, cstf, sums);
    k3_se<<<dim3(BB), dim3(192), 0, stream>>>(
        sums, se_red_w, se_red_b, se_exp_w, se_exp_b, sews);
    k4_proj<<<dim3(HWSZ/64, BB), dim3(256), 0, stream>>>(
        EY, sews, Aproj, pscf, pshf, x, (float*)d_out);
}